// Round 6
// baseline (385.914 us; speedup 1.0000x reference)
//
#include <hip/hip_runtime.h>
#include <hip/hip_bf16.h>

static constexpr int VN = 500000;   // nodes
static constexpr int DD = 128;      // feature dim
static constexpr int NE = 1000000;  // hyperedges
static constexpr int KE = 8;        // nodes per hyperedge
static constexpr int CC = 16;       // layer-3 width
static constexpr int H1 = 8;        // hidden width
static constexpr int EW = 64;       // ELL width (cnt[v] <= edges containing v ~ Poisson(16); P(>=64)~1e-18)

typedef float fvec4 __attribute__((ext_vector_type(4)));
typedef int   ivec4 __attribute__((ext_vector_type(4)));

// Fused: fill[v]=0 ; proj[v] = X[v,:]·rv ; A[v,0:8] = X[v,:]·W1 (raw M1)
__global__ __launch_bounds__(256) void k_row(const float* __restrict__ X,
                                             const float* __restrict__ rv,
                                             const float* __restrict__ W1,
                                             float* __restrict__ proj,
                                             float* __restrict__ A,
                                             int* __restrict__ fill) {
    int v = blockIdx.x * 256 + threadIdx.x;
    if (v >= VN) return;
    fill[v] = 0;
    const fvec4* xr = reinterpret_cast<const fvec4*>(X + (size_t)v * DD);
    const float4* rr = reinterpret_cast<const float4*>(rv);
    float accP = 0.f;
    float accM[H1];
#pragma unroll
    for (int j = 0; j < H1; ++j) accM[j] = 0.f;
#pragma unroll 8
    for (int k = 0; k < DD / 4; ++k) {
        fvec4 x = __builtin_nontemporal_load(&xr[k]);
        float4 r = rr[k];
        accP += x.x * r.x + x.y * r.y + x.z * r.z + x.w * r.w;
#pragma unroll
        for (int q = 0; q < 4; ++q) {
            float xv = (q == 0) ? x.x : (q == 1) ? x.y : (q == 2) ? x.z : x.w;
            const float4 wa = *reinterpret_cast<const float4*>(W1 + (size_t)(k * 4 + q) * H1);
            const float4 wb = *reinterpret_cast<const float4*>(W1 + (size_t)(k * 4 + q) * H1 + 4);
            accM[0] += xv * wa.x; accM[1] += xv * wa.y;
            accM[2] += xv * wa.z; accM[3] += xv * wa.w;
            accM[4] += xv * wb.x; accM[5] += xv * wb.y;
            accM[6] += xv * wb.z; accM[7] += xv * wb.w;
        }
    }
    proj[v] = accP;
    float4* a4 = reinterpret_cast<float4*>(A + (size_t)v * H1);
    a4[0] = make_float4(accM[0], accM[1], accM[2], accM[3]);
    a4[1] = make_float4(accM[4], accM[5], accM[6], accM[7]);
}

// Per-edge argmax/argmin of proj (first occurrence wins) + direct ELL place.
__global__ __launch_bounds__(256) void k_place(const int* __restrict__ E,
                                               const float* __restrict__ proj,
                                               int* __restrict__ fill,
                                               int* __restrict__ ell) {
    int e = blockIdx.x * 256 + threadIdx.x;
    if (e >= NE) return;
    const ivec4* er = reinterpret_cast<const ivec4*>(E + (size_t)e * KE);
    ivec4 e0 = __builtin_nontemporal_load(&er[0]);
    ivec4 e1 = __builtin_nontemporal_load(&er[1]);
    int ids[KE] = {e0.x, e0.y, e0.z, e0.w, e1.x, e1.y, e1.z, e1.w};
    float p[KE];
#pragma unroll
    for (int j = 0; j < KE; ++j) p[j] = proj[ids[j]];
    float bestMax = p[0], bestMin = p[0];
    int idMax = ids[0], idMin = ids[0];
#pragma unroll
    for (int j = 1; j < KE; ++j) {
        if (p[j] > bestMax) { bestMax = p[j]; idMax = ids[j]; }
        if (p[j] < bestMin) { bestMin = p[j]; idMin = ids[j]; }
    }
    // claim both slots first (ILP), then the dependent scattered stores (nt)
    int ps = atomicAdd(fill + idMax, 1);
    int pi = atomicAdd(fill + idMin, 1);
    if (ps < EW) __builtin_nontemporal_store(idMin, ell + (size_t)idMax * EW + ps);
    if (pi < EW) __builtin_nontemporal_store(idMax, ell + (size_t)idMin * EW + pi);
}

// Cooperative 4-lane gather SpMM + bias + ReLU + tiny matmul.
// PRE: Min rows already dinv-scaled (M'); else scale each neighbor by dinv[c].
// Y[v] = dinv[v]*(ownscale*own + 0.125*sum_c dinvc*Min[c]); Mout = dinv*(relu(Y+b)@W)
template <int FIN, int FOUT, int RSI, int RSO, bool PRE>
__global__ __launch_bounds__(256) void k_glayer4(const int* __restrict__ ell,
                                                 const int* __restrict__ fill,
                                                 const float* __restrict__ bias,
                                                 const float* __restrict__ W,
                                                 const float* __restrict__ Min,
                                                 float* __restrict__ Mout) {
    int t = blockIdx.x * 256 + threadIdx.x;
    int v = t >> 2, g = t & 3;
    if (v >= VN) return;
    int deg = fill[v];
    float di = rsqrtf(1.0f + 0.125f * (float)deg);
    float s[FIN];
#pragma unroll
    for (int j = 0; j < FIN; ++j) s[j] = 0.f;
    const int* row = ell + (size_t)v * EW;
    int p = g;
    // 2 neighbor rows in flight per lane (x4 lanes = 8 per node)
    for (; p + 4 < deg; p += 8) {
        int c0 = row[p], c1 = row[p + 4];
        float sc0 = 1.f, sc1 = 1.f;
        if (!PRE) {
            sc0 = rsqrtf(1.0f + 0.125f * (float)fill[c0]);
            sc1 = rsqrtf(1.0f + 0.125f * (float)fill[c1]);
        }
        const float4* r0 = reinterpret_cast<const float4*>(Min + (size_t)c0 * RSI);
        const float4* r1 = reinterpret_cast<const float4*>(Min + (size_t)c1 * RSI);
        float4 t0[FIN / 4], t1[FIN / 4];
#pragma unroll
        for (int j = 0; j < FIN / 4; ++j) t0[j] = r0[j];
#pragma unroll
        for (int j = 0; j < FIN / 4; ++j) t1[j] = r1[j];
#pragma unroll
        for (int j = 0; j < FIN / 4; ++j) {
            s[4 * j]     += sc0 * t0[j].x + sc1 * t1[j].x;
            s[4 * j + 1] += sc0 * t0[j].y + sc1 * t1[j].y;
            s[4 * j + 2] += sc0 * t0[j].z + sc1 * t1[j].z;
            s[4 * j + 3] += sc0 * t0[j].w + sc1 * t1[j].w;
        }
    }
    if (p < deg) {
        int c = row[p];
        float sc = 1.f;
        if (!PRE) sc = rsqrtf(1.0f + 0.125f * (float)fill[c]);
        const float4* cr = reinterpret_cast<const float4*>(Min + (size_t)c * RSI);
#pragma unroll
        for (int j = 0; j < FIN / 4; ++j) {
            float4 tt = cr[j];
            s[4 * j] += sc * tt.x; s[4 * j + 1] += sc * tt.y;
            s[4 * j + 2] += sc * tt.z; s[4 * j + 3] += sc * tt.w;
        }
    }
    // butterfly: all 4 lanes end with the full neighbor sum
#pragma unroll
    for (int j = 0; j < FIN; ++j) {
        s[j] += __shfl_xor(s[j], 1);
        s[j] += __shfl_xor(s[j], 2);
    }
    // own row (same line for all 4 lanes -> L1 broadcast)
    const float4* mr = reinterpret_cast<const float4*>(Min + (size_t)v * RSI);
    float own[FIN];
#pragma unroll
    for (int j = 0; j < FIN / 4; ++j) {
        float4 tt = mr[j];
        own[4 * j] = tt.x; own[4 * j + 1] = tt.y;
        own[4 * j + 2] = tt.z; own[4 * j + 3] = tt.w;
    }
    float osc = PRE ? 1.0f : di;
    float h[FIN];
#pragma unroll
    for (int j = 0; j < FIN; ++j) {
        float y = di * (osc * own[j] + 0.125f * s[j]) + bias[j];
        h[j] = y > 0.f ? y : 0.f;
    }
    // each lane computes FOUT/4 output columns (stores coalesce within group)
#pragma unroll
    for (int c = 0; c < FOUT / 4; ++c) {
        int col = g + 4 * c;
        float m = 0.f;
#pragma unroll
        for (int j = 0; j < FIN; ++j) m += h[j] * W[j * FOUT + col];
        Mout[(size_t)v * RSO + col] = di * m;
    }
}

// Final: 4-lane gather of Y3 (PRE rows, RS=16), relu(Y3+b3), dot fc_w, sigmoid
__global__ __launch_bounds__(256) void k_gfinal4(const int* __restrict__ ell,
                                                 const int* __restrict__ fill,
                                                 const float* __restrict__ b3,
                                                 const float* __restrict__ fcw,
                                                 const float* __restrict__ fcb,
                                                 const float* __restrict__ Min,
                                                 float* __restrict__ out) {
    int t = blockIdx.x * 256 + threadIdx.x;
    int v = t >> 2, g = t & 3;
    if (v >= VN) return;
    int deg = fill[v];
    float di = rsqrtf(1.0f + 0.125f * (float)deg);
    float s[CC];
#pragma unroll
    for (int j = 0; j < CC; ++j) s[j] = 0.f;
    const int* row = ell + (size_t)v * EW;
    int p = g;
    for (; p + 4 < deg; p += 8) {
        int c0 = row[p], c1 = row[p + 4];
        const float4* r0 = reinterpret_cast<const float4*>(Min + (size_t)c0 * CC);
        const float4* r1 = reinterpret_cast<const float4*>(Min + (size_t)c1 * CC);
        float4 t0[CC / 4], t1[CC / 4];
#pragma unroll
        for (int j = 0; j < CC / 4; ++j) t0[j] = r0[j];
#pragma unroll
        for (int j = 0; j < CC / 4; ++j) t1[j] = r1[j];
#pragma unroll
        for (int j = 0; j < CC / 4; ++j) {
            s[4 * j]     += t0[j].x + t1[j].x;
            s[4 * j + 1] += t0[j].y + t1[j].y;
            s[4 * j + 2] += t0[j].z + t1[j].z;
            s[4 * j + 3] += t0[j].w + t1[j].w;
        }
    }
    if (p < deg) {
        int c = row[p];
        const float4* cr = reinterpret_cast<const float4*>(Min + (size_t)c * CC);
#pragma unroll
        for (int j = 0; j < CC / 4; ++j) {
            float4 tt = cr[j];
            s[4 * j] += tt.x; s[4 * j + 1] += tt.y;
            s[4 * j + 2] += tt.z; s[4 * j + 3] += tt.w;
        }
    }
#pragma unroll
    for (int j = 0; j < CC; ++j) {
        s[j] += __shfl_xor(s[j], 1);
        s[j] += __shfl_xor(s[j], 2);
    }
    const float4* mr = reinterpret_cast<const float4*>(Min + (size_t)v * CC);
    float own[CC];
#pragma unroll
    for (int j = 0; j < CC / 4; ++j) {
        float4 tt = mr[j];
        own[4 * j] = tt.x; own[4 * j + 1] = tt.y;
        own[4 * j + 2] = tt.z; own[4 * j + 3] = tt.w;
    }
    // head: lanes split the 16 columns, butterfly-reduce the scalar
    float acc = 0.f;
#pragma unroll
    for (int c = 0; c < CC / 4; ++c) {
        int col = g + 4 * c;
        float y = di * (own[col] + 0.125f * s[col]) + b3[col];
        float hh = y > 0.f ? y : 0.f;
        acc += hh * fcw[col];
    }
    acc += __shfl_xor(acc, 1);
    acc += __shfl_xor(acc, 2);
    if (g == 0) out[v] = 1.f / (1.f + expf(-(acc + fcb[0])));
}

extern "C" void kernel_launch(void* const* d_in, const int* in_sizes, int n_in,
                              void* d_out, int out_size, void* d_ws, size_t ws_size,
                              hipStream_t stream) {
    const float* X   = (const float*)d_in[0];
    const int*   E   = (const int*)d_in[1];
    const float* rv  = (const float*)d_in[2];
    const float* W1  = (const float*)d_in[3];
    const float* b1  = (const float*)d_in[4];
    const float* W2  = (const float*)d_in[5];
    const float* b2  = (const float*)d_in[6];
    const float* W3  = (const float*)d_in[7];
    const float* b3  = (const float*)d_in[8];
    const float* fcw = (const float*)d_in[9];
    const float* fcb = (const float*)d_in[10];
    float* out = (float*)d_out;

    float* ws = (float*)d_ws;
    float* A    = ws;                          // [VN x 8]  16 MB (raw M1)
    float* B    = ws + 4000000;                // [VN x 8]  16 MB (M2')
    float* C    = ws + 8000000;                // [VN x 16] 32 MB (M3')
    float* proj = ws + 16000000;               // [VN]
    int*   fill = (int*)(ws + 16500000);       // [VN] slot counters == deg
    int*   ell  = (int*)(ws + 17000000);       // [VN x 64] 128 MB

    dim3 blk(256);
    int gV  = (VN + 255) / 256;
    int gE  = (NE + 255) / 256;
    int gV4 = (VN * 4 + 255) / 256;

    k_row<<<gV, blk, 0, stream>>>(X, rv, W1, proj, A, fill);
    k_place<<<gE, blk, 0, stream>>>(E, proj, fill, ell);

    // layer 1: A(raw M1,RS8) -> B(M2',RS8)   (neighbor dinv on the fly)
    k_glayer4<8, 8, 8, 8, false><<<gV4, blk, 0, stream>>>(ell, fill, b1, W2, A, B);
    // layer 2: B(M2',RS8) -> C(M3',RS16)
    k_glayer4<8, 16, 8, 16, true><<<gV4, blk, 0, stream>>>(ell, fill, b2, W3, B, C);
    // layer 3 + head: C(M3',RS16) -> out
    k_gfinal4<<<gV4, blk, 0, stream>>>(ell, fill, b3, fcw, fcb, C, out);
}